// Round 12
// baseline (412.358 us; speedup 1.0000x reference)
//
#include <hip/hip_runtime.h>
#include <hip/hip_bf16.h>

// Causal flash attention fwd. B=2,H=16,S=2048,D=128, fp32 io, bf16 MFMA.
// R12: 8-wave blocks, K-split inside the block, NO workspace.
// Post-mortems: R10/R11 split-K via global partials always L3-thrashes
// (FETCH 49->195..308MB) -> net loss. R7/R9's ~93us limit is LATENCY at
// 1 wave/SIMD: the light co-resident block finishes early and the heavy
// block's 4 waves have zero SIMD-level overlap (6.5k cyc/round, MFMA only
// 256 of it). Fix: 512-thread blocks, waves (qsub,kg): kg splits the 64-key
// tile in half; each wave owns its own online (m,l,O) state, merged ONCE per
// q-tile through LDS (block-local, no global traffic). 2 waves/SIMD during
// the solo phase, 16 MFMA/round/wave, acc=16 regs (QK^T liveness 32 below
// R7 -> fits 128-VGPR cap of launch_bounds(512,4) = 2 blocks/CU, LDS 68KB).
// Inner round math/swizzles/permlane-P/defer-max/lgkmcnt-barrier from R9.
constexpr int Bb = 2, Hh = 16, Ss = 2048, Dd = 128;
constexpr int BM = 128, BN = 64;
constexpr int NQT = Ss / BM;                       // 16
constexpr float SCALE = 0.088388347648318447f * 1.4426950408889634f; // 1/sqrt(128)*log2e

typedef __attribute__((ext_vector_type(8))) short bf16x8;
typedef __attribute__((ext_vector_type(16))) float f32x16;
typedef __attribute__((ext_vector_type(4))) float f32x4v;
typedef __attribute__((ext_vector_type(4))) int int4v;
typedef __attribute__((ext_vector_type(2))) int int2v;

__device__ __forceinline__ unsigned cvtpk(float lo, float hi) {
  unsigned r;
  asm("v_cvt_pk_bf16_f32 %0, %1, %2" : "=v"(r) : "v"(lo), "v"(hi));
  return r;                                    // RNE packed bf16 pair
}
__device__ __forceinline__ float exp2hw(float x) {
  float r;
  asm("v_exp_f32 %0, %1" : "=v"(r) : "v"(x));  // hardware exp2
  return r;
}
__device__ __forceinline__ void permswap(unsigned &x, unsigned &y) {
  asm("v_permlane32_swap_b32 %0, %1" : "+v"(x), "+v"(y));
}
__device__ __forceinline__ float fcomp(float4 f, int j) {
  return j == 0 ? f.x : (j == 1 ? f.y : (j == 2 ? f.z : f.w));
}
// Barrier without vmcnt drain (LDS visibility only); prefetch loads cross it.
__device__ __forceinline__ void block_sync_lds() {
  __builtin_amdgcn_sched_barrier(0);
  asm volatile("s_waitcnt lgkmcnt(0)" ::: "memory");
  __builtin_amdgcn_s_barrier();
  __builtin_amdgcn_sched_barrier(0);
}

__global__ __launch_bounds__(512, 4)
void fa_fwd_kernel(const float* __restrict__ q, const float* __restrict__ k,
                   const float* __restrict__ v, float* __restrict__ out) {
  // [0,32K): K dbuf (2 x 16KB, swizzled rows of 256B)
  // [32K,64K): V dbuf (2 x 16KB, Vt rows of 128B)
  // whole 64KB reused as 4 x 16KB merge slabs (one per qsub) at tile end.
  __shared__ __align__(16) char lds[65536];
  __shared__ float2 mlbuf[8][64];                 // per-wave (m, l) at merge

  const int tid = threadIdx.x;
  const int wave = tid >> 6, lane = tid & 63;
  const int l31 = lane & 31, hi = lane >> 5, hi4 = hi * 4;
  const int qsub = wave >> 1, kg = wave & 1;      // q-subtile, key-half
  const int bid = blockIdx.x;
  const int bh = bid & 31;
  const int r2 = bid >> 5;
  const int qt = (r2 < 8) ? (15 - r2) : (r2 - 8); // complementary pairing

  const float* qb = q + (size_t)bh * Ss * Dd;
  const float* kb = k + (size_t)bh * Ss * Dd;
  const float* vb = v + (size_t)bh * Ss * Dd;
  const int qv = qsub * 32 + l31;                 // q-row in tile this lane owns

  char* const Klds0 = lds;
  char* const Klds1 = lds + 16384;
  char* const Vlds0 = lds + 32768;
  char* const Vlds1 = lds + 49152;

  // ---- Q fragments (scale*log2e folded). B-operand: col q=l31, d=16ks+8hi+j.
  bf16x8 qf[8];
  {
    const float* qr = qb + (size_t)(qt * BM + qv) * Dd + hi * 8;
    #pragma unroll
    for (int ks = 0; ks < 8; ++ks) {
      float4 a = *(const float4*)(qr + ks * 16);
      float4 b = *(const float4*)(qr + ks * 16 + 4);
      int4v t;
      t[0] = (int)cvtpk(a.x * SCALE, a.y * SCALE);
      t[1] = (int)cvtpk(a.z * SCALE, a.w * SCALE);
      t[2] = (int)cvtpk(b.x * SCALE, b.y * SCALE);
      t[3] = (int)cvtpk(b.z * SCALE, b.w * SCALE);
      qf[ks] = __builtin_bit_cast(bf16x8, t);
    }
  }

  // ---- staging geometry (512 threads): K: 2 rows x 8d each; V: 4 keys x 4d.
  const int krow0 = tid >> 4;            // 0..31
  const int kblk  = tid & 15;
  const int kswz  = kblk ^ (krow0 & 15); // rows krow0, krow0+32 share row&15
  const int vkg = tid >> 5;              // 0..15: keys vkg*4..+3
  const int vdq = tid & 31;              // d0 = vdq*4

  float4 ka[2], kc[2];                   // K prefetch regs
  float4 vr[4];                          // V prefetch regs

  auto load_k = [&](int kt) {
    const float* Kg = kb + (size_t)(kt * BN) * Dd + kblk * 8;
    #pragma unroll
    for (int i = 0; i < 2; ++i) {
      ka[i] = *(const float4*)(Kg + (size_t)(krow0 + 32 * i) * Dd);
      kc[i] = *(const float4*)(Kg + (size_t)(krow0 + 32 * i) * Dd + 4);
    }
  };
  auto load_v = [&](int kt) {
    const float* Vg = vb + (size_t)(kt * BN + vkg * 4) * Dd + vdq * 4;
    #pragma unroll
    for (int r = 0; r < 4; ++r)
      vr[r] = *(const float4*)(Vg + (size_t)r * Dd);
  };
  auto stage_k = [&](char* Kb) {
    #pragma unroll
    for (int i = 0; i < 2; ++i) {
      int4v t;
      t[0] = (int)cvtpk(ka[i].x, ka[i].y);
      t[1] = (int)cvtpk(ka[i].z, ka[i].w);
      t[2] = (int)cvtpk(kc[i].x, kc[i].y);
      t[3] = (int)cvtpk(kc[i].z, kc[i].w);
      *(int4v*)(Kb + (krow0 + 32 * i) * 256 + kswz * 16) = t;
    }
  };
  auto stage_v = [&](char* Vb) {
    #pragma unroll
    for (int j = 0; j < 4; ++j) {
      int d = vdq * 4 + j;
      int f7 = (d ^ (d >> 3)) & 7;
      int2v t;
      t[0] = (int)cvtpk(fcomp(vr[0], j), fcomp(vr[1], j));
      t[1] = (int)cvtpk(fcomp(vr[2], j), fcomp(vr[3], j));
      // 8B half-block: block vkg>>1 (keys /8), half vkg&1
      *(int2v*)(Vb + d * 128 + ((vkg >> 1) ^ f7) * 16 + (vkg & 1) * 8) = t;
    }
  };

  // O^T accumulators for this wave's 32 rows x its 32-key half contributions.
  f32x16 o[4];
  #pragma unroll
  for (int i = 0; i < 4; ++i) o[i] = (f32x16)(0.0f);
  float mrow = -3.0e38f, lrow = 0.0f;

  const int nkt = 2 * qt + 2;

  load_k(0); load_v(0);
  stage_k(Klds0); stage_v(Vlds0);
  load_k(1); load_v(1);                  // nkt >= 2 always

  for (int kt = 0; kt < nkt; ++kt) {
    block_sync_lds();                    // buf[cur] staged; prefetch in flight
    const int cur = kt & 1;
    const char* Kc = cur ? Klds1 : Klds0;
    const char* Vc = cur ? Vlds1 : Vlds0;
    const bool more = kt + 1 < nkt;
    const int kn = (kt + 2 < nkt) ? kt + 2 : nkt - 1;

    // wave-uniform: does this wave's key-half intersect the causal region?
    const bool live = (qt * 128 + qsub * 32 + 31 - kt * 64 - kg * 32) >= 0;

    bf16x8 pf[2];
    if (live) {
      // ---- S^T = K Q^T over this wave's 32-key half (8 MFMA, K=128).
      f32x16 acc = (f32x16)(0.0f);
      const int krow = kg * 32 + l31;
      const int kr15 = krow & 15;
      __builtin_amdgcn_s_setprio(1);
      #pragma unroll
      for (int ks = 0; ks < 8; ++ks) {
        int bswz = (2 * ks + hi) ^ kr15;
        bf16x8 kf = *(const bf16x8*)(Kc + krow * 256 + bswz * 16);
        acc = __builtin_amdgcn_mfma_f32_32x32x16_bf16(kf, qf[ks], acc, 0, 0, 0);
      }
      __builtin_amdgcn_s_setprio(0);

      // ---- causal mask (diagonal k-tiles only)
      if (kt + 2 >= nkt) {
        const int thr2 = qt * 128 + qv - kt * 64 - kg * 32;
        #pragma unroll
        for (int r = 0; r < 16; ++r) {
          int keyloc = (r & 3) + 8 * (r >> 2) + hi4;
          if (keyloc > thr2) acc[r] = -1.0e30f;
        }
      }

      // ---- online softmax (log2 domain), 4-way tree partials
      float mp0 = acc[0], mp1 = acc[1], mp2 = acc[2], mp3 = acc[3];
      #pragma unroll
      for (int r = 4; r < 16; r += 4) {
        mp0 = fmaxf(mp0, acc[r + 0]);
        mp1 = fmaxf(mp1, acc[r + 1]);
        mp2 = fmaxf(mp2, acc[r + 2]);
        mp3 = fmaxf(mp3, acc[r + 3]);
      }
      float mx = fmaxf(fmaxf(mp0, mp1), fmaxf(mp2, mp3));
      mx = fmaxf(mx, __shfl_xor(mx, 32, 64));

      if (!__all(mx - mrow <= 8.0f)) {   // defer-max THR=8
        float mn = fmaxf(mrow, mx);
        float al = exp2hw(mrow - mn);
        mrow = mn;
        lrow *= al;
        #pragma unroll
        for (int dt = 0; dt < 4; ++dt)
          #pragma unroll
          for (int r = 0; r < 16; ++r) o[dt][r] *= al;
      }

      float rp0 = 0.f, rp1 = 0.f, rp2 = 0.f, rp3 = 0.f;
      #pragma unroll
      for (int r = 0; r < 16; r += 4) {
        float p0 = exp2hw(acc[r + 0] - mrow);
        float p1 = exp2hw(acc[r + 1] - mrow);
        float p2 = exp2hw(acc[r + 2] - mrow);
        float p3 = exp2hw(acc[r + 3] - mrow);
        acc[r + 0] = p0; acc[r + 1] = p1;
        acc[r + 2] = p2; acc[r + 3] = p3;
        rp0 += p0; rp1 += p1; rp2 += p2; rp3 += p3;
      }
      lrow += (rp0 + rp1) + (rp2 + rp3);

      // ---- P^T B-frags (keys local 16*ks2+8g+j) via cvt_pk + permlane32_swap
      #pragma unroll
      for (int ks2 = 0; ks2 < 2; ++ks2) {
        int s8 = ks2 * 8;
        unsigned A0 = cvtpk(acc[s8 + 0], acc[s8 + 1]);
        unsigned A1 = cvtpk(acc[s8 + 2], acc[s8 + 3]);
        unsigned B0 = cvtpk(acc[s8 + 4], acc[s8 + 5]);
        unsigned B1 = cvtpk(acc[s8 + 6], acc[s8 + 7]);
        permswap(A0, B0);
        permswap(A1, B1);
        int4v pw; pw[0] = (int)A0; pw[1] = (int)A1; pw[2] = (int)B0; pw[3] = (int)B1;
        pf[ks2] = __builtin_bit_cast(bf16x8, pw);
      }
    }

    // ---- stage K(kt+1), then issue load_k(kt+2) into the freed regs.
    if (more) {
      __builtin_amdgcn_sched_barrier(0);
      stage_k(cur ? Klds0 : Klds1);
      load_k(kn);
      __builtin_amdgcn_sched_barrier(0);
    }

    // ---- O^T += V^T P^T over this wave's key half (8 MFMA).
    if (live) {
      __builtin_amdgcn_s_setprio(1);
      #pragma unroll
      for (int dt = 0; dt < 4; ++dt) {
        int rowd = dt * 32 + l31;
        int f7 = (rowd ^ (rowd >> 3)) & 7;
        #pragma unroll
        for (int ks2 = 0; ks2 < 2; ++ks2) {
          int bswz = (kg * 4 + 2 * ks2 + hi) ^ f7;
          bf16x8 vf = *(const bf16x8*)(Vc + rowd * 128 + bswz * 16);
          o[dt] = __builtin_amdgcn_mfma_f32_32x32x16_bf16(vf, pf[ks2], o[dt], 0, 0, 0);
        }
      }
      __builtin_amdgcn_s_setprio(0);
    }

    // ---- stage V(kt+1), then issue load_v(kt+2).
    if (more) {
      __builtin_amdgcn_sched_barrier(0);
      stage_v(cur ? Vlds0 : Vlds1);
      load_v(kn);
    }
  }

  // ---- merge the two key-half states per (qsub, q-row) through LDS.
  float lsum = lrow + __shfl_xor(lrow, 32, 64);
  mlbuf[wave][lane] = make_float2(mrow, lsum);
  __syncthreads();                       // all PV reads done; lds reusable
  float2 ml1 = mlbuf[wave ^ 1][lane];    // partner wave, same (l31,hi)
  float M = fmaxf(mrow, ml1.x);
  float w0 = exp2hw(mrow - M), w1 = exp2hw(ml1.x - M);
  float ltot = lsum * w0 + ml1.y * w1;

  char* const slab = lds + qsub * 16384;
  if (kg == 1) {
    #pragma unroll
    for (int dt = 0; dt < 4; ++dt)
      #pragma unroll
      for (int g = 0; g < 4; ++g) {
        int r16 = dt * 4 + g;
        int blk = r16 ^ (l31 & 15);      // spread banks
        f32x4v w;
        w[0] = o[dt][g * 4 + 0]; w[1] = o[dt][g * 4 + 1];
        w[2] = o[dt][g * 4 + 2]; w[3] = o[dt][g * 4 + 3];
        *(f32x4v*)(slab + lane * 256 + blk * 16) = w;
      }
  }
  __syncthreads();
  if (kg == 0) {
    const float linv = 1.0f / ltot;
    float* ob = out + ((size_t)bh * Ss + qt * BM + qv) * Dd;
    #pragma unroll
    for (int dt = 0; dt < 4; ++dt)
      #pragma unroll
      for (int g = 0; g < 4; ++g) {
        int r16 = dt * 4 + g;
        int blk = r16 ^ (l31 & 15);
        f32x4v o1 = *(const f32x4v*)(slab + lane * 256 + blk * 16);
        float4 wv;
        wv.x = (o[dt][g * 4 + 0] * w0 + o1[0] * w1) * linv;
        wv.y = (o[dt][g * 4 + 1] * w0 + o1[1] * w1) * linv;
        wv.z = (o[dt][g * 4 + 2] * w0 + o1[2] * w1) * linv;
        wv.w = (o[dt][g * 4 + 3] * w0 + o1[3] * w1) * linv;
        *(float4*)(ob + dt * 32 + g * 8 + hi4) = wv;   // d = dt*32 + 8g + 4hi + c
      }
  }
}

extern "C" void kernel_launch(void* const* d_in, const int* in_sizes, int n_in,
                              void* d_out, int out_size, void* d_ws, size_t ws_size,
                              hipStream_t stream) {
  const float* q = (const float*)d_in[0];
  const float* k = (const float*)d_in[1];
  const float* v = (const float*)d_in[2];
  float* out = (float*)d_out;
  dim3 grid(Bb * Hh * NQT);   // 512
  dim3 block(512);            // 8 waves: (qsub 0..3) x (kg 0..1)
  hipLaunchKernelGGL(fa_fwd_kernel, grid, block, 0, stream, q, k, v, out);
}